// Round 7
// baseline (233.380 us; speedup 1.0000x reference)
//
#include <hip/hip_runtime.h>
#include <hip/hip_bf16.h>

#define D_MODEL 2048
#define NQH 32
#define NKVH 8
#define HD 64
#define SEQ 2048
#define BATCH 2
#define MTOT (BATCH * SEQ) // 4096

typedef __attribute__((ext_vector_type(8))) short short8;
typedef __attribute__((ext_vector_type(4))) float floatx4;
typedef __attribute__((ext_vector_type(16))) float f32x16;

// Q pre-scale: (1/sqrt(64)) * log2(e)  -> softmax via exp2
#define QSCALE 0.18033688011112042f

#if __has_builtin(__builtin_amdgcn_exp2f)
#define EXP2(x) __builtin_amdgcn_exp2f(x)
#else
#define EXP2(x) exp2f(x)
#endif

static __device__ inline unsigned cvtpk(float lo, float hi) {
  unsigned r;
  asm("v_cvt_pk_bf16_f32 %0, %1, %2" : "=v"(r) : "v"(lo), "v"(hi));
  return r;
}
// a' = (a.lo, b.lo), b' = (a.hi, b.hi)
#define PLSWAP(a, b) asm("v_permlane32_swap_b32 %0, %1" : "+v"(a), "+v"(b))

// async global -> LDS, 16B per lane; lds base must be wave-uniform
__device__ inline void gload_lds16(const __hip_bfloat16* g, short* lds) {
  __builtin_amdgcn_global_load_lds(
      (const __attribute__((address_space(1))) void*)g,
      (__attribute__((address_space(3))) void*)lds, 16, 0, 0);
}

// ---------------- fp32 -> bf16 elementwise (vectorized) ----------------
__global__ __launch_bounds__(256) void convx_k(const float* __restrict__ x,
                                               __hip_bfloat16* __restrict__ xb,
                                               int n4) {
  int i = blockIdx.x * 256 + threadIdx.x;
  int stride = gridDim.x * 256;
  for (; i < n4; i += stride) {
    float4 v = reinterpret_cast<const float4*>(x)[i];
    union { __hip_bfloat16 h[4]; uint2 u; } cv;
    cv.h[0] = __float2bfloat16(v.x);
    cv.h[1] = __float2bfloat16(v.y);
    cv.h[2] = __float2bfloat16(v.z);
    cv.h[3] = __float2bfloat16(v.w);
    reinterpret_cast<uint2*>(xb)[i] = cv.u;
  }
}

// ---------------- W [K][N] fp32  ->  W^T [N][K] bf16 ----------------
__global__ __launch_bounds__(256) void transw_k(const float* __restrict__ W,
                                                __hip_bfloat16* __restrict__ Wt,
                                                int Kd, int Nd) {
  __shared__ float t[32][33];
  int n0 = blockIdx.x * 32, k0 = blockIdx.y * 32;
  int tx = threadIdx.x, ty = threadIdx.y;
#pragma unroll
  for (int j = 0; j < 32; j += 8)
    t[ty + j][tx] = W[(size_t)(k0 + ty + j) * Nd + n0 + tx];
  __syncthreads();
#pragma unroll
  for (int j = 0; j < 32; j += 8)
    Wt[(size_t)(n0 + ty + j) * Kd + k0 + tx] = __float2bfloat16(t[tx][ty + j]);
}

// ---------------- deep-pipelined GEMM  C[m][n] = A[m][k] * Bt[n][k] ------
// 256x128 tile, BK=64, 8 waves (2Mx4N), 3 LDS buffers (144KB), 2 phases per
// K-tile of 16 MFMA each. Stages for tile t+2 issued 3/phase; counted
// s_waitcnt vmcnt(6) once per K-tile (never 0 in the main loop).
// LDS rows 64 bf16 = 8 chunks of 16B, phys_chunk = logical ^ (row&7):
// frag reads are 2-way (free); staging source is inverse-swizzled, dest linear.
// MODE 0: fp32 out [4096][2048]. MODE 1: fused QKV scatter epilogue.
template <int MODE>
__global__ __launch_bounds__(512, 1) void gemm8p_k(
    const __hip_bfloat16* __restrict__ A,
    const __hip_bfloat16* __restrict__ B0,
    const __hip_bfloat16* __restrict__ B1,
    const __hip_bfloat16* __restrict__ B2,
    float* __restrict__ Cf,
    __hip_bfloat16* __restrict__ O0,
    __hip_bfloat16* __restrict__ O1,
    __hip_bfloat16* __restrict__ O2) {
  constexpr int Kd = D_MODEL;
  constexpr int NT = Kd / 64;                 // 32 K-tiles
  constexpr int NB = (MODE == 0) ? 16 : 24;   // N/128
  constexpr int NWG = 16 * NB;

  __shared__ short Asb[3][16384]; // 3 x [256 rows][64 k] bf16
  __shared__ short Bsb[3][8192];  // 3 x [128 rows][64 k] bf16

  // bijective XCD swizzle (NWG % 8 == 0)
  const int bid = blockIdx.x;
  const int swz = (bid & 7) * (NWG / 8) + (bid >> 3);
  const int by = swz / NB, bx = swz % NB;
  const int m0 = by * 256, n0 = bx * 128;

  const __hip_bfloat16* Bt;
  if (MODE == 0) {
    Bt = B0 + (size_t)n0 * Kd;
  } else {
    if (n0 < 2048) Bt = B0 + (size_t)n0 * Kd;
    else if (n0 < 2560) Bt = B1 + (size_t)(n0 - 2048) * Kd;
    else Bt = B2 + (size_t)(n0 - 2560) * Kd;
  }
  const __hip_bfloat16* Ab = A + (size_t)m0 * Kd;

  const int tid = threadIdx.x, w = tid >> 6, l = tid & 63;
  const int wm = w >> 2, wn = w & 3;     // wave row (0..1), col (0..3)
  const int lc = l & 15, l4 = l >> 4;

  // ---- staging geometry (per 64-row load L): thread covers row w*8+(l>>3),
  // source chunk inverse-swizzled; LDS dest linear (base + lane*16).
  const int srow = w * 8 + (l >> 3);
  const int scc = (l & 7) ^ (l >> 3);

#define STAGE_A(L, SB, KT) \
  gload_lds16(Ab + (size_t)((L)*64 + srow) * Kd + (KT) + scc * 8, &Asb[SB][(L)*4096 + w * 512])
#define STAGE_B(L, SB, KT) \
  gload_lds16(Bt + (size_t)((L)*64 + srow) * Kd + (KT) + scc * 8, &Bsb[SB][(L)*4096 + w * 512])

  floatx4 acc[8][2] = {};

  // frag read offsets: row r (r&7 == lc&7 since bases are multiples of 16),
  // chunk = (kk*4 + l4) ^ (lc&7)
  int cx[2];
#pragma unroll
  for (int kk = 0; kk < 2; ++kk) cx[kk] = (((kk * 4 + l4) ^ (lc & 7)) * 8);
  const int abase = (wm * 128 + lc) * 64;
  const int bbase = (wn * 32 + lc) * 64;

  // ---- prologue: stage tiles 0 (buf0) and 1 (buf1); wait tile 0 only ----
  STAGE_A(0, 0, 0); STAGE_A(1, 0, 0); STAGE_A(2, 0, 0); STAGE_A(3, 0, 0);
  STAGE_B(0, 0, 0); STAGE_B(1, 0, 0);
  STAGE_A(0, 1, 64); STAGE_A(1, 1, 64); STAGE_A(2, 1, 64); STAGE_A(3, 1, 64);
  STAGE_B(0, 1, 64); STAGE_B(1, 1, 64);
  asm volatile("s_waitcnt vmcnt(6)" ::: "memory");
  __builtin_amdgcn_s_barrier();

  short8 af[4][2], bfr[2][2];

  for (int t = 0; t < NT; ++t) {
    const int rb = t % 3, sb = (t + 2) % 3;
    const int ksrc = ((t + 2) % NT) * 64; // wrap at tail (dead data, never read)
    const short* Ar = Asb[rb];
    const short* Br = Bsb[rb];

    // ================= phase 0 (qm = 0) =================
#pragma unroll
    for (int mi = 0; mi < 4; ++mi)
#pragma unroll
      for (int kk = 0; kk < 2; ++kk)
        af[mi][kk] = *reinterpret_cast<const short8*>(&Ar[abase + mi * 1024 + cx[kk]]);
#pragma unroll
    for (int ni = 0; ni < 2; ++ni)
#pragma unroll
      for (int kk = 0; kk < 2; ++kk)
        bfr[ni][kk] = *reinterpret_cast<const short8*>(&Br[bbase + ni * 1024 + cx[kk]]);

    STAGE_A(0, sb, ksrc); STAGE_A(1, sb, ksrc); STAGE_B(0, sb, ksrc);

    __builtin_amdgcn_s_barrier();
    asm volatile("s_waitcnt lgkmcnt(0)" ::: "memory");
    __builtin_amdgcn_sched_barrier(0);
    __builtin_amdgcn_s_setprio(1);
#pragma unroll
    for (int mi = 0; mi < 4; ++mi)
#pragma unroll
      for (int ni = 0; ni < 2; ++ni)
#pragma unroll
        for (int kk = 0; kk < 2; ++kk)
          acc[mi][ni] = __builtin_amdgcn_mfma_f32_16x16x32_bf16(
              af[mi][kk], bfr[ni][kk], acc[mi][ni], 0, 0, 0);
    __builtin_amdgcn_s_setprio(0);
    __builtin_amdgcn_s_barrier();

    // ================= phase 1 (qm = 1) =================
#pragma unroll
    for (int mi = 0; mi < 4; ++mi)
#pragma unroll
      for (int kk = 0; kk < 2; ++kk)
        af[mi][kk] = *reinterpret_cast<const short8*>(&Ar[abase + 4096 + mi * 1024 + cx[kk]]);

    STAGE_A(2, sb, ksrc); STAGE_A(3, sb, ksrc); STAGE_B(1, sb, ksrc);

    // wait tile t+1's 6 loads (t+2's 6 stay in flight)
    asm volatile("s_waitcnt vmcnt(6)" ::: "memory");
    __builtin_amdgcn_s_barrier();
    asm volatile("s_waitcnt lgkmcnt(0)" ::: "memory");
    __builtin_amdgcn_sched_barrier(0);
    __builtin_amdgcn_s_setprio(1);
#pragma unroll
    for (int mi = 0; mi < 4; ++mi)
#pragma unroll
      for (int ni = 0; ni < 2; ++ni)
#pragma unroll
        for (int kk = 0; kk < 2; ++kk)
          acc[4 + mi][ni] = __builtin_amdgcn_mfma_f32_16x16x32_bf16(
              af[mi][kk], bfr[ni][kk], acc[4 + mi][ni], 0, 0, 0);
    __builtin_amdgcn_s_setprio(0);
    __builtin_amdgcn_s_barrier();
  }
#undef STAGE_A
#undef STAGE_B

  // ---- epilogue ----
#pragma unroll
  for (int qm = 0; qm < 2; ++qm)
#pragma unroll
    for (int mi = 0; mi < 4; ++mi)
#pragma unroll
      for (int ni = 0; ni < 2; ++ni)
#pragma unroll
        for (int i = 0; i < 4; ++i) {
          int m = m0 + wm * 128 + qm * 64 + mi * 16 + l4 * 4 + i;
          int ncol = n0 + wn * 32 + ni * 16 + lc;
          float v = acc[qm * 4 + mi][ni][i];
          if (MODE == 0) {
            Cf[(size_t)m * 2048 + ncol] = v;
          } else {
            int bb = m >> 11, s = m & 2047;
            if (ncol < 2048) {
              int hh = ncol >> 6, dd = ncol & 63;
              O0[(((size_t)bb * NQH + hh) * SEQ + s) * HD + dd] = __float2bfloat16(v * QSCALE);
            } else if (ncol < 2560) {
              int c2 = ncol - 2048;
              int hh = c2 >> 6, dd = c2 & 63;
              O1[(((size_t)bb * NKVH + hh) * SEQ + s) * HD + dd] = __float2bfloat16(v);
            } else {
              int c2 = ncol - 2560;
              int hh = c2 >> 6, dd = c2 & 63;
              O2[(((size_t)bb * NKVH + hh) * HD + dd) * SEQ + s] = __float2bfloat16(v);
            }
          }
        }
}

// ---------------- Flash attention: coalesced staging, compact body ------
// (unchanged from R6: 93 us steady-state)
__global__ __launch_bounds__(256, 4) void attn_k(const __hip_bfloat16* __restrict__ Qb,
                                                 const __hip_bfloat16* __restrict__ Kb,
                                                 const __hip_bfloat16* __restrict__ Vtb,
                                                 __hip_bfloat16* __restrict__ Ao) {
  __shared__ short Ks[2][64 * 64];
  __shared__ short Vs[2][64 * 64];
  __shared__ float Ls[4][32];

  const int bid = blockIdx.x;
  const int xcd = bid & 7, j = bid >> 3;
  const int g = xcd * 2 + (j >> 6), wv = j & 63;
  const int b = g >> 3, kh = g & 7;
  const int h = kh * 4 + (wv >> 4), qt = wv & 15;

  const int tid = threadIdx.x, w = tid >> 6, l = tid & 63;
  const int q5 = l & 31, hl = l >> 5;

  const __hip_bfloat16* Qp = Qb + (((size_t)b * NQH + h) * SEQ + qt * 128 + w * 32) * HD;
  const __hip_bfloat16* Kp = Kb + ((size_t)b * NKVH + kh) * SEQ * HD;
  const __hip_bfloat16* Vp = Vtb + ((size_t)b * NKVH + kh) * HD * SEQ;

  short8 qf[4];
#pragma unroll
  for (int ks = 0; ks < 4; ++ks)
    qf[ks] = *reinterpret_cast<const short8*>(Qp + (size_t)q5 * HD + ks * 16 + hl * 8);

  f32x16 acc0 = {}, acc1 = {};
  float lsum = 0.f;

  const int rg = l >> 3;
  const int cc = (l & 7) ^ (rg & 7);
  const __hip_bfloat16* sK = Kp + (size_t)(16 * w + rg) * HD + cc * 8;
  const __hip_bfloat16* sV = Vp + (size_t)(16 * w + rg) * SEQ + cc * 8;

  int fo[4];
#pragma unroll
  for (int jj = 0; jj < 4; ++jj)
    fo[jj] = q5 * 64 + (((jj * 2 + hl) ^ (q5 & 7)) * 8);

  gload_lds16(sK, &Ks[0][1024 * w]);
  gload_lds16(sK + 8 * HD, &Ks[0][1024 * w + 512]);
  gload_lds16(sV, &Vs[0][1024 * w]);
  gload_lds16(sV + 8 * (size_t)SEQ, &Vs[0][1024 * w + 512]);
  sK += 64 * HD;
  sV += 64;
  __syncthreads();

  for (int kb = 0; kb < SEQ / 64; ++kb) {
    const short* Kt = Ks[kb & 1];
    const short* Vt = Vs[kb & 1];

    if (kb + 1 < SEQ / 64) {
      short* Kn = Ks[(kb & 1) ^ 1];
      short* Vn = Vs[(kb & 1) ^ 1];
      gload_lds16(sK, &Kn[1024 * w]);
      gload_lds16(sK + 8 * HD, &Kn[1024 * w + 512]);
      gload_lds16(sV, &Vn[1024 * w]);
      gload_lds16(sV + 8 * (size_t)SEQ, &Vn[1024 * w + 512]);
      sK += 64 * HD;
      sV += 64;
    }

    short8 kf0[4], kf1[4];
#pragma unroll
    for (int ks = 0; ks < 4; ++ks) {
      kf0[ks] = *reinterpret_cast<const short8*>(&Kt[fo[ks]]);
      kf1[ks] = *reinterpret_cast<const short8*>(&Kt[fo[ks] + 2048]);
    }
    f32x16 st0 = {}, st1 = {};
    __builtin_amdgcn_s_setprio(1);
#pragma unroll
    for (int ks = 0; ks < 4; ++ks) {
      st0 = __builtin_amdgcn_mfma_f32_32x32x16_bf16(kf0[ks], qf[ks], st0, 0, 0, 0);
      st1 = __builtin_amdgcn_mfma_f32_32x32x16_bf16(kf1[ks], qf[ks], st1, 0, 0, 0);
    }
    __builtin_amdgcn_s_setprio(0);

    float ps = 0.f;
    unsigned u0[8], u1[8];
#pragma unroll
    for (int jj = 0; jj < 8; ++jj) {
      float e0 = EXP2(st0[2 * jj]), e1 = EXP2(st0[2 * jj + 1]);
      float f0 = EXP2(st1[2 * jj]), f1 = EXP2(st1[2 * jj + 1]);
      ps += (e0 + e1) + (f0 + f1);
      u0[jj] = cvtpk(e0, e1);
      u1[jj] = cvtpk(f0, f1);
    }
    lsum += ps;

    short8 vf0[4], vf1[4];
#pragma unroll
    for (int t = 0; t < 4; ++t) {
      vf0[t] = *reinterpret_cast<const short8*>(&Vt[fo[t]]);
      vf1[t] = *reinterpret_cast<const short8*>(&Vt[fo[t] + 2048]);
    }

    PLSWAP(u0[0], u0[2]); PLSWAP(u0[1], u0[3]);
    PLSWAP(u0[4], u0[6]); PLSWAP(u0[5], u0[7]);
    PLSWAP(u1[0], u1[2]); PLSWAP(u1[1], u1[3]);
    PLSWAP(u1[4], u1[6]); PLSWAP(u1[5], u1[7]);

    __builtin_amdgcn_s_setprio(1);
#pragma unroll
    for (int t = 0; t < 4; ++t) {
      union { unsigned w4[4]; short8 s8; } pa;
      pa.w4[0] = (t >> 1 ? u1 : u0)[(t & 1) * 4 + 0];
      pa.w4[1] = (t >> 1 ? u1 : u0)[(t & 1) * 4 + 1];
      pa.w4[2] = (t >> 1 ? u1 : u0)[(t & 1) * 4 + 2];
      pa.w4[3] = (t >> 1 ? u1 : u0)[(t & 1) * 4 + 3];
      acc0 = __builtin_amdgcn_mfma_f32_32x32x16_bf16(pa.s8, vf0[t], acc0, 0, 0, 0);
      acc1 = __builtin_amdgcn_mfma_f32_32x32x16_bf16(pa.s8, vf1[t], acc1, 0, 0, 0);
    }
    __builtin_amdgcn_s_setprio(0);
    __syncthreads();
  }

  {
    float v = lsum;
    v += __shfl_xor(v, 32);
    if (l < 32) Ls[w][l] = v;
  }
  __syncthreads();

  const size_t obase = (size_t)b * SEQ + qt * 128 + w * 32;
  float inv[16];
#pragma unroll
  for (int r = 0; r < 16; ++r)
    inv[r] = 1.0f / Ls[w][(r & 3) + 8 * (r >> 2) + 4 * hl];
#pragma unroll
  for (int r = 0; r < 16; ++r) {
    int q = (r & 3) + 8 * (r >> 2) + 4 * hl;
    Ao[(obase + q) * D_MODEL + h * HD + q5] = __float2bfloat16(acc0[r] * inv[r]);
    Ao[(obase + q) * D_MODEL + h * HD + 32 + q5] = __float2bfloat16(acc1[r] * inv[r]);
  }
}

// ---------------- host ----------------
extern "C" void kernel_launch(void* const* d_in, const int* in_sizes, int n_in,
                              void* d_out, int out_size, void* d_ws, size_t ws_size,
                              hipStream_t stream) {
  const float* x  = (const float*)d_in[0];
  const float* Wq = (const float*)d_in[1];
  const float* Wk = (const float*)d_in[2];
  const float* Wv = (const float*)d_in[3];
  const float* Wo = (const float*)d_in[4];
  float* out = (float*)d_out;

  __hip_bfloat16* p = (__hip_bfloat16*)d_ws;
  __hip_bfloat16* xb  = p;
  __hip_bfloat16* Wqt = xb  + (size_t)MTOT * D_MODEL;
  __hip_bfloat16* Wkt = Wqt + (size_t)D_MODEL * D_MODEL;
  __hip_bfloat16* Wvt = Wkt + (size_t)512 * D_MODEL;
  __hip_bfloat16* Wot = Wvt + (size_t)512 * D_MODEL;
  __hip_bfloat16* Qb  = Wot + (size_t)D_MODEL * D_MODEL;
  __hip_bfloat16* Kb  = Qb  + (size_t)MTOT * D_MODEL;
  __hip_bfloat16* Vtb = Kb  + (size_t)BATCH * NKVH * SEQ * HD;
  __hip_bfloat16* Ab  = Vtb + (size_t)BATCH * NKVH * SEQ * HD;

  convx_k<<<2048, 256, 0, stream>>>(x, xb, MTOT * D_MODEL / 4);
  transw_k<<<dim3(D_MODEL / 32, D_MODEL / 32), dim3(32, 8), 0, stream>>>(Wq, Wqt, D_MODEL, D_MODEL);
  transw_k<<<dim3(512 / 32, D_MODEL / 32), dim3(32, 8), 0, stream>>>(Wk, Wkt, D_MODEL, 512);
  transw_k<<<dim3(512 / 32, D_MODEL / 32), dim3(32, 8), 0, stream>>>(Wv, Wvt, D_MODEL, 512);
  transw_k<<<dim3(D_MODEL / 32, D_MODEL / 32), dim3(32, 8), 0, stream>>>(Wo, Wot, D_MODEL, D_MODEL);

  // fused QKV projection: N = 2048 (Q) + 512 (K) + 512 (V) = 3072
  gemm8p_k<1><<<dim3(16 * 24), 512, 0, stream>>>(xb, Wqt, Wkt, Wvt,
                                                 nullptr, Qb, Kb, Vtb);
  attn_k<<<dim3(1024), 256, 0, stream>>>(Qb, Kb, Vtb, Ab);
  // output projection -> fp32
  gemm8p_k<0><<<dim3(16 * 16), 512, 0, stream>>>(Ab, Wot, nullptr, nullptr,
                                                 out, nullptr, nullptr, nullptr);
}

// Round 8
// 222.327 us; speedup vs baseline: 1.0497x; 1.0497x over previous
//
#include <hip/hip_runtime.h>
#include <hip/hip_bf16.h>

#define D_MODEL 2048
#define NQH 32
#define NKVH 8
#define HD 64
#define SEQ 2048
#define BATCH 2
#define MTOT (BATCH * SEQ) // 4096

typedef __attribute__((ext_vector_type(8))) short short8;
typedef __attribute__((ext_vector_type(4))) float floatx4;
typedef __attribute__((ext_vector_type(16))) float f32x16;

// Q pre-scale: (1/sqrt(64)) * log2(e)  -> softmax via exp2
#define QSCALE 0.18033688011112042f

#if __has_builtin(__builtin_amdgcn_exp2f)
#define EXP2(x) __builtin_amdgcn_exp2f(x)
#else
#define EXP2(x) exp2f(x)
#endif

static __device__ inline unsigned cvtpk(float lo, float hi) {
  unsigned r;
  asm("v_cvt_pk_bf16_f32 %0, %1, %2" : "=v"(r) : "v"(lo), "v"(hi));
  return r;
}
// a' = (a.lo, b.lo), b' = (a.hi, b.hi)
#define PLSWAP(a, b) asm("v_permlane32_swap_b32 %0, %1" : "+v"(a), "+v"(b))

// async global -> LDS, 16B per lane; lds base must be wave-uniform
__device__ inline void gload_lds16(const __hip_bfloat16* g, short* lds) {
  __builtin_amdgcn_global_load_lds(
      (const __attribute__((address_space(1))) void*)g,
      (__attribute__((address_space(3))) void*)lds, 16, 0, 0);
}

// ---------------- fp32 -> bf16 elementwise (vectorized) ----------------
__global__ __launch_bounds__(256) void convx_k(const float* __restrict__ x,
                                               __hip_bfloat16* __restrict__ xb,
                                               int n4) {
  int i = blockIdx.x * 256 + threadIdx.x;
  int stride = gridDim.x * 256;
  for (; i < n4; i += stride) {
    float4 v = reinterpret_cast<const float4*>(x)[i];
    union { __hip_bfloat16 h[4]; uint2 u; } cv;
    cv.h[0] = __float2bfloat16(v.x);
    cv.h[1] = __float2bfloat16(v.y);
    cv.h[2] = __float2bfloat16(v.z);
    cv.h[3] = __float2bfloat16(v.w);
    reinterpret_cast<uint2*>(xb)[i] = cv.u;
  }
}

// ---------- all four W [K][N] fp32 -> W^T [N][K] bf16, one launch --------
__global__ __launch_bounds__(256) void transw_all_k(
    const float* __restrict__ Wq, const float* __restrict__ Wk,
    const float* __restrict__ Wv, const float* __restrict__ Wo,
    __hip_bfloat16* __restrict__ Wqt, __hip_bfloat16* __restrict__ Wkt,
    __hip_bfloat16* __restrict__ Wvt, __hip_bfloat16* __restrict__ Wot) {
  __shared__ float t[32][33];
  const int z = blockIdx.z;
  const int Nd = (z == 1 || z == 2) ? 512 : 2048;
  const int n0 = blockIdx.x * 32;
  if (n0 >= Nd) return;
  const float* W = (z == 0) ? Wq : (z == 1) ? Wk : (z == 2) ? Wv : Wo;
  __hip_bfloat16* Wt = (z == 0) ? Wqt : (z == 1) ? Wkt : (z == 2) ? Wvt : Wot;
  const int Kd = D_MODEL;
  const int k0 = blockIdx.y * 32;
  const int tx = threadIdx.x, ty = threadIdx.y;
#pragma unroll
  for (int j = 0; j < 32; j += 8)
    t[ty + j][tx] = W[(size_t)(k0 + ty + j) * Nd + n0 + tx];
  __syncthreads();
#pragma unroll
  for (int j = 0; j < 32; j += 8)
    Wt[(size_t)(n0 + ty + j) * Kd + k0 + tx] = __float2bfloat16(t[tx][ty + j]);
}

// ---------------- deep-pipelined GEMM  C[m][n] = A[m][k] * Bt[n][k] ------
// 256x128 tile, BK=64, 8 waves as 4Mx2N (wave tile 64x64), 3 LDS buffers,
// 2 phases per K-tile split by K-HALF: each phase = 8 ds_read_b128 + 16 MFMA
// (m201 read:MFMA ratio). acc[4][4] accumulates across both phases.
// Counted s_waitcnt vmcnt(6) once per K-tile (never 0 in the main loop).
// LDS rows 64 bf16 = 8 chunks of 16B, phys_chunk = logical ^ (row&7):
// frag reads 2-way (free); staging source inverse-swizzled, dest linear.
template <int MODE>
__global__ __launch_bounds__(512, 1) void gemm8p_k(
    const __hip_bfloat16* __restrict__ A,
    const __hip_bfloat16* __restrict__ B0,
    const __hip_bfloat16* __restrict__ B1,
    const __hip_bfloat16* __restrict__ B2,
    float* __restrict__ Cf,
    __hip_bfloat16* __restrict__ O0,
    __hip_bfloat16* __restrict__ O1,
    __hip_bfloat16* __restrict__ O2) {
  constexpr int Kd = D_MODEL;
  constexpr int NT = Kd / 64;                 // 32 K-tiles
  constexpr int NB = (MODE == 0) ? 16 : 24;   // N/128
  constexpr int NWG = 16 * NB;

  __shared__ short Asb[3][16384]; // 3 x [256 rows][64 k] bf16
  __shared__ short Bsb[3][8192];  // 3 x [128 rows][64 k] bf16

  // bijective XCD swizzle (NWG % 8 == 0)
  const int bid = blockIdx.x;
  const int swz = (bid & 7) * (NWG / 8) + (bid >> 3);
  const int by = swz / NB, bx = swz % NB;
  const int m0 = by * 256, n0 = bx * 128;

  const __hip_bfloat16* Bt;
  if (MODE == 0) {
    Bt = B0 + (size_t)n0 * Kd;
  } else {
    if (n0 < 2048) Bt = B0 + (size_t)n0 * Kd;
    else if (n0 < 2560) Bt = B1 + (size_t)(n0 - 2048) * Kd;
    else Bt = B2 + (size_t)(n0 - 2560) * Kd;
  }
  const __hip_bfloat16* Ab = A + (size_t)m0 * Kd;

  const int tid = threadIdx.x, w = tid >> 6, l = tid & 63;
  const int wm = w >> 1, wn = w & 1;     // wave row (0..3), col (0..1)
  const int lc = l & 15, l4 = l >> 4;

  // staging: per 64-row load L, thread covers row w*8+(l>>3), src chunk
  // inverse-swizzled; LDS dest linear (base + lane*16).
  const int srow = w * 8 + (l >> 3);
  const int scc = (l & 7) ^ ((l >> 3) & 7);

#define STAGE_A(L, SB, KT) \
  gload_lds16(Ab + (size_t)((L)*64 + srow) * Kd + (KT) + scc * 8, &Asb[SB][(L)*4096 + w * 512])
#define STAGE_B(L, SB, KT) \
  gload_lds16(Bt + (size_t)((L)*64 + srow) * Kd + (KT) + scc * 8, &Bsb[SB][(L)*4096 + w * 512])

  floatx4 acc[4][4] = {};

  // frag read offsets: row r (r&7 == lc&7, bases multiple of 16),
  // logical chunk kk*4+l4, phys = chunk ^ (lc&7)
  int cx[2];
#pragma unroll
  for (int kk = 0; kk < 2; ++kk) cx[kk] = (((kk * 4 + l4) ^ (lc & 7)) * 8);
  const int abase = (wm * 64 + lc) * 64;
  const int bbase = (wn * 64 + lc) * 64;

  // ---- prologue: stage tiles 0 (buf0) and 1 (buf1); wait tile 0 only ----
  STAGE_A(0, 0, 0); STAGE_A(1, 0, 0); STAGE_A(2, 0, 0); STAGE_A(3, 0, 0);
  STAGE_B(0, 0, 0); STAGE_B(1, 0, 0);
  STAGE_A(0, 1, 64); STAGE_A(1, 1, 64); STAGE_A(2, 1, 64); STAGE_A(3, 1, 64);
  STAGE_B(0, 1, 64); STAGE_B(1, 1, 64);
  asm volatile("s_waitcnt vmcnt(6)" ::: "memory");
  __builtin_amdgcn_s_barrier();

  short8 af[4], bfr[4];

  for (int t = 0; t < NT; ++t) {
    const int rb = t % 3, sb = (t + 2) % 3;
    const int ksrc = ((t + 2) % NT) * 64; // wrap at tail (dead data, never read)
    const short* Ar = Asb[rb];
    const short* Br = Bsb[rb];

    // ================= phase 0 (k-half 0) =================
#pragma unroll
    for (int mi = 0; mi < 4; ++mi)
      af[mi] = *reinterpret_cast<const short8*>(&Ar[abase + mi * 1024 + cx[0]]);
#pragma unroll
    for (int ni = 0; ni < 4; ++ni)
      bfr[ni] = *reinterpret_cast<const short8*>(&Br[bbase + ni * 1024 + cx[0]]);

    STAGE_A(0, sb, ksrc); STAGE_A(1, sb, ksrc); STAGE_B(0, sb, ksrc);

    __builtin_amdgcn_s_barrier();
    asm volatile("s_waitcnt lgkmcnt(0)" ::: "memory");
    __builtin_amdgcn_sched_barrier(0);
    __builtin_amdgcn_s_setprio(1);
#pragma unroll
    for (int mi = 0; mi < 4; ++mi)
#pragma unroll
      for (int ni = 0; ni < 4; ++ni)
        acc[mi][ni] = __builtin_amdgcn_mfma_f32_16x16x32_bf16(
            af[mi], bfr[ni], acc[mi][ni], 0, 0, 0);
    __builtin_amdgcn_s_setprio(0);
    __builtin_amdgcn_s_barrier();

    // ================= phase 1 (k-half 1) =================
#pragma unroll
    for (int mi = 0; mi < 4; ++mi)
      af[mi] = *reinterpret_cast<const short8*>(&Ar[abase + mi * 1024 + cx[1]]);
#pragma unroll
    for (int ni = 0; ni < 4; ++ni)
      bfr[ni] = *reinterpret_cast<const short8*>(&Br[bbase + ni * 1024 + cx[1]]);

    STAGE_A(2, sb, ksrc); STAGE_A(3, sb, ksrc); STAGE_B(1, sb, ksrc);

    // wait tile t+1's 6 loads (tile t+2's 6 stay in flight)
    asm volatile("s_waitcnt vmcnt(6)" ::: "memory");
    __builtin_amdgcn_s_barrier();
    asm volatile("s_waitcnt lgkmcnt(0)" ::: "memory");
    __builtin_amdgcn_sched_barrier(0);
    __builtin_amdgcn_s_setprio(1);
#pragma unroll
    for (int mi = 0; mi < 4; ++mi)
#pragma unroll
      for (int ni = 0; ni < 4; ++ni)
        acc[mi][ni] = __builtin_amdgcn_mfma_f32_16x16x32_bf16(
            af[mi], bfr[ni], acc[mi][ni], 0, 0, 0);
    __builtin_amdgcn_s_setprio(0);
    __builtin_amdgcn_s_barrier();
  }
#undef STAGE_A
#undef STAGE_B

  // ---- epilogue: C/D layout col = lane&15, row = (lane>>4)*4 + i ----
#pragma unroll
  for (int mi = 0; mi < 4; ++mi)
#pragma unroll
    for (int ni = 0; ni < 4; ++ni)
#pragma unroll
      for (int i = 0; i < 4; ++i) {
        int m = m0 + wm * 64 + mi * 16 + l4 * 4 + i;
        int ncol = n0 + wn * 64 + ni * 16 + lc;
        float v = acc[mi][ni][i];
        if (MODE == 0) {
          Cf[(size_t)m * 2048 + ncol] = v;
        } else {
          int bb = m >> 11, s = m & 2047;
          if (ncol < 2048) {
            int hh = ncol >> 6, dd = ncol & 63;
            O0[(((size_t)bb * NQH + hh) * SEQ + s) * HD + dd] = __float2bfloat16(v * QSCALE);
          } else if (ncol < 2560) {
            int c2 = ncol - 2048;
            int hh = c2 >> 6, dd = c2 & 63;
            O1[(((size_t)bb * NKVH + hh) * SEQ + s) * HD + dd] = __float2bfloat16(v);
          } else {
            int c2 = ncol - 2560;
            int hh = c2 >> 6, dd = c2 & 63;
            O2[(((size_t)bb * NKVH + hh) * HD + dd) * SEQ + s] = __float2bfloat16(v);
          }
        }
      }
}

// ---------------- Flash attention: coalesced staging, compact body ------
// (unchanged from R6: 93 us steady-state)
__global__ __launch_bounds__(256, 4) void attn_k(const __hip_bfloat16* __restrict__ Qb,
                                                 const __hip_bfloat16* __restrict__ Kb,
                                                 const __hip_bfloat16* __restrict__ Vtb,
                                                 __hip_bfloat16* __restrict__ Ao) {
  __shared__ short Ks[2][64 * 64];
  __shared__ short Vs[2][64 * 64];
  __shared__ float Ls[4][32];

  const int bid = blockIdx.x;
  const int xcd = bid & 7, j = bid >> 3;
  const int g = xcd * 2 + (j >> 6), wv = j & 63;
  const int b = g >> 3, kh = g & 7;
  const int h = kh * 4 + (wv >> 4), qt = wv & 15;

  const int tid = threadIdx.x, w = tid >> 6, l = tid & 63;
  const int q5 = l & 31, hl = l >> 5;

  const __hip_bfloat16* Qp = Qb + (((size_t)b * NQH + h) * SEQ + qt * 128 + w * 32) * HD;
  const __hip_bfloat16* Kp = Kb + ((size_t)b * NKVH + kh) * SEQ * HD;
  const __hip_bfloat16* Vp = Vtb + ((size_t)b * NKVH + kh) * HD * SEQ;

  short8 qf[4];
#pragma unroll
  for (int ks = 0; ks < 4; ++ks)
    qf[ks] = *reinterpret_cast<const short8*>(Qp + (size_t)q5 * HD + ks * 16 + hl * 8);

  f32x16 acc0 = {}, acc1 = {};
  float lsum = 0.f;

  const int rg = l >> 3;
  const int cc = (l & 7) ^ (rg & 7);
  const __hip_bfloat16* sK = Kp + (size_t)(16 * w + rg) * HD + cc * 8;
  const __hip_bfloat16* sV = Vp + (size_t)(16 * w + rg) * SEQ + cc * 8;

  int fo[4];
#pragma unroll
  for (int jj = 0; jj < 4; ++jj)
    fo[jj] = q5 * 64 + (((jj * 2 + hl) ^ (q5 & 7)) * 8);

  gload_lds16(sK, &Ks[0][1024 * w]);
  gload_lds16(sK + 8 * HD, &Ks[0][1024 * w + 512]);
  gload_lds16(sV, &Vs[0][1024 * w]);
  gload_lds16(sV + 8 * (size_t)SEQ, &Vs[0][1024 * w + 512]);
  sK += 64 * HD;
  sV += 64;
  __syncthreads();

  for (int kb = 0; kb < SEQ / 64; ++kb) {
    const short* Kt = Ks[kb & 1];
    const short* Vt = Vs[kb & 1];

    if (kb + 1 < SEQ / 64) {
      short* Kn = Ks[(kb & 1) ^ 1];
      short* Vn = Vs[(kb & 1) ^ 1];
      gload_lds16(sK, &Kn[1024 * w]);
      gload_lds16(sK + 8 * HD, &Kn[1024 * w + 512]);
      gload_lds16(sV, &Vn[1024 * w]);
      gload_lds16(sV + 8 * (size_t)SEQ, &Vn[1024 * w + 512]);
      sK += 64 * HD;
      sV += 64;
    }

    short8 kf0[4], kf1[4];
#pragma unroll
    for (int ks = 0; ks < 4; ++ks) {
      kf0[ks] = *reinterpret_cast<const short8*>(&Kt[fo[ks]]);
      kf1[ks] = *reinterpret_cast<const short8*>(&Kt[fo[ks] + 2048]);
    }
    f32x16 st0 = {}, st1 = {};
    __builtin_amdgcn_s_setprio(1);
#pragma unroll
    for (int ks = 0; ks < 4; ++ks) {
      st0 = __builtin_amdgcn_mfma_f32_32x32x16_bf16(kf0[ks], qf[ks], st0, 0, 0, 0);
      st1 = __builtin_amdgcn_mfma_f32_32x32x16_bf16(kf1[ks], qf[ks], st1, 0, 0, 0);
    }
    __builtin_amdgcn_s_setprio(0);

    float ps = 0.f;
    unsigned u0[8], u1[8];
#pragma unroll
    for (int jj = 0; jj < 8; ++jj) {
      float e0 = EXP2(st0[2 * jj]), e1 = EXP2(st0[2 * jj + 1]);
      float f0 = EXP2(st1[2 * jj]), f1 = EXP2(st1[2 * jj + 1]);
      ps += (e0 + e1) + (f0 + f1);
      u0[jj] = cvtpk(e0, e1);
      u1[jj] = cvtpk(f0, f1);
    }
    lsum += ps;

    short8 vf0[4], vf1[4];
#pragma unroll
    for (int t = 0; t < 4; ++t) {
      vf0[t] = *reinterpret_cast<const short8*>(&Vt[fo[t]]);
      vf1[t] = *reinterpret_cast<const short8*>(&Vt[fo[t] + 2048]);
    }

    PLSWAP(u0[0], u0[2]); PLSWAP(u0[1], u0[3]);
    PLSWAP(u0[4], u0[6]); PLSWAP(u0[5], u0[7]);
    PLSWAP(u1[0], u1[2]); PLSWAP(u1[1], u1[3]);
    PLSWAP(u1[4], u1[6]); PLSWAP(u1[5], u1[7]);

    __builtin_amdgcn_s_setprio(1);
#pragma unroll
    for (int t = 0; t < 4; ++t) {
      union { unsigned w4[4]; short8 s8; } pa;
      pa.w4[0] = (t >> 1 ? u1 : u0)[(t & 1) * 4 + 0];
      pa.w4[1] = (t >> 1 ? u1 : u0)[(t & 1) * 4 + 1];
      pa.w4[2] = (t >> 1 ? u1 : u0)[(t & 1) * 4 + 2];
      pa.w4[3] = (t >> 1 ? u1 : u0)[(t & 1) * 4 + 3];
      acc0 = __builtin_amdgcn_mfma_f32_32x32x16_bf16(pa.s8, vf0[t], acc0, 0, 0, 0);
      acc1 = __builtin_amdgcn_mfma_f32_32x32x16_bf16(pa.s8, vf1[t], acc1, 0, 0, 0);
    }
    __builtin_amdgcn_s_setprio(0);
    __syncthreads();
  }

  {
    float v = lsum;
    v += __shfl_xor(v, 32);
    if (l < 32) Ls[w][l] = v;
  }
  __syncthreads();

  const size_t obase = (size_t)b * SEQ + qt * 128 + w * 32;
  float inv[16];
#pragma unroll
  for (int r = 0; r < 16; ++r)
    inv[r] = 1.0f / Ls[w][(r & 3) + 8 * (r >> 2) + 4 * hl];
#pragma unroll
  for (int r = 0; r < 16; ++r) {
    int q = (r & 3) + 8 * (r >> 2) + 4 * hl;
    Ao[(obase + q) * D_MODEL + h * HD + q5] = __float2bfloat16(acc0[r] * inv[r]);
    Ao[(obase + q) * D_MODEL + h * HD + 32 + q5] = __float2bfloat16(acc1[r] * inv[r]);
  }
}

// ---------------- host ----------------
extern "C" void kernel_launch(void* const* d_in, const int* in_sizes, int n_in,
                              void* d_out, int out_size, void* d_ws, size_t ws_size,
                              hipStream_t stream) {
  const float* x  = (const float*)d_in[0];
  const float* Wq = (const float*)d_in[1];
  const float* Wk = (const float*)d_in[2];
  const float* Wv = (const float*)d_in[3];
  const float* Wo = (const float*)d_in[4];
  float* out = (float*)d_out;

  __hip_bfloat16* p = (__hip_bfloat16*)d_ws;
  __hip_bfloat16* xb  = p;
  __hip_bfloat16* Wqt = xb  + (size_t)MTOT * D_MODEL;
  __hip_bfloat16* Wkt = Wqt + (size_t)D_MODEL * D_MODEL;
  __hip_bfloat16* Wvt = Wkt + (size_t)512 * D_MODEL;
  __hip_bfloat16* Wot = Wvt + (size_t)512 * D_MODEL;
  __hip_bfloat16* Qb  = Wot + (size_t)D_MODEL * D_MODEL;
  __hip_bfloat16* Kb  = Qb  + (size_t)MTOT * D_MODEL;
  __hip_bfloat16* Vtb = Kb  + (size_t)BATCH * NKVH * SEQ * HD;
  __hip_bfloat16* Ab  = Vtb + (size_t)BATCH * NKVH * SEQ * HD;

  convx_k<<<2048, 256, 0, stream>>>(x, xb, MTOT * D_MODEL / 4);
  transw_all_k<<<dim3(64, 64, 4), dim3(32, 8), 0, stream>>>(Wq, Wk, Wv, Wo,
                                                            Wqt, Wkt, Wvt, Wot);

  // fused QKV projection: N = 2048 (Q) + 512 (K) + 512 (V) = 3072
  gemm8p_k<1><<<dim3(16 * 24), 512, 0, stream>>>(xb, Wqt, Wkt, Wvt,
                                                 nullptr, Qb, Kb, Vtb);
  attn_k<<<dim3(1024), 256, 0, stream>>>(Qb, Kb, Vtb, Ab);
  // output projection -> fp32
  gemm8p_k<0><<<dim3(16 * 16), 512, 0, stream>>>(Ab, Wot, nullptr, nullptr,
                                                 out, nullptr, nullptr, nullptr);
}